// Round 1
// baseline (11966.949 us; speedup 1.0000x reference)
//
#include <hip/hip_runtime.h>
#include <hip/hip_cooperative_groups.h>
#include <math.h>

namespace cg = cooperative_groups;

#define NB 64       // batch
#define NT 128      // time steps
#define NE 64       // embedding
#define NU 512      // units
#define NG 2048     // 4*U
#define NV 2000     // vocab
#define BU (NB*NU)

// ---------------------------------------------------------------------------
// Cooperative LSTM: 256 blocks x 512 threads.
// Block (rg, cg): rg = bk>>5 owns rows brow0..brow0+8, cg = bk&31 owns units
// u0..u0+16 (-> 64 z-columns: 4 gates x 16 units; lane = column).
// Wave wv (8 per block) owns k-slice [wv*64, wv*64+64) and e-slice
// [wv*8, wv*8+8). Weights live in VGPRs; h is read with wave-uniform vector
// loads (pointer laundered through asm so the compiler cannot use s_load,
// which is not coherent with the cross-block h writes between grid syncs).
// ---------------------------------------------------------------------------
__global__ __launch_bounds__(512, 1)
void lstm_coop(const float* __restrict__ emb, const int* __restrict__ ids,
               const float* __restrict__ Wx, const float* __restrict__ Wh,
               const float* __restrict__ bias,
               const float* __restrict__ h0, const float* __restrict__ c0,
               float* __restrict__ Hout, float* __restrict__ hping,
               float* __restrict__ cfin)
{
    cg::grid_group gg = cg::this_grid();
    __shared__ float psum[8][8][64];           // [wave][row][col] = 16 KB

    const int tid  = threadIdx.x;
    const int wv   = tid >> 6;                 // 0..7 k-slice
    const int cl   = tid & 63;                 // column lane
    const int bk   = blockIdx.x;
    const int rg   = bk >> 5;                  // 0..7
    const int cgi  = bk & 31;                  // 0..31
    const int brow0 = rg * 8;
    const int u0    = cgi * 16;
    const int gate  = cl >> 4;                 // 0..3
    const int uu_c  = cl & 15;
    const int colg  = gate * 512 + u0 + uu_c;  // global z column of this lane

    // per-thread weight registers
    float w[64];
#pragma unroll
    for (int kk = 0; kk < 64; ++kk) w[kk] = Wh[(size_t)(wv * 64 + kk) * NG + colg];
    float wx[8];
#pragma unroll
    for (int ee = 0; ee < 8; ++ee) wx[ee] = Wx[(size_t)(wv * 8 + ee) * NG + colg];

    // gate/update threads: tid<128 -> (row bl, unit uug)
    const int bl  = tid >> 4;                  // valid for tid<128: 0..7
    const int uug = tid & 15;
    float creg = 0.f;
    float b4[4] = {0.f, 0.f, 0.f, 0.f};
    if (tid < 128) {
#pragma unroll
        for (int g = 0; g < 4; ++g) b4[g] = bias[g * 512 + u0 + uug];
        const int hi = (brow0 + bl) * NU + u0 + uug;
        creg = c0 ? c0[hi] : 0.f;
        hping[hi] = h0 ? h0[hi] : 0.f;         // slot 0 = h state before t=0
    }
    gg.sync();

    for (int t = 0; t < NT; ++t) {
        const float* hr = hping + (t & 1) * BU;
        asm volatile("" : "+v"(hr));           // force vector-path loads for h

        float acc[8];
#pragma unroll
        for (int b = 0; b < 8; ++b) {
            const float4* hb4 = reinterpret_cast<const float4*>(hr + (brow0 + b) * NU + wv * 64);
            float a0 = 0.f, a1 = 0.f, a2 = 0.f, a3 = 0.f;
#pragma unroll
            for (int k4 = 0; k4 < 16; k4 += 4) {
                float4 v0 = hb4[k4 + 0];
                a0 += v0.x * w[4 * k4 + 0] + v0.y * w[4 * k4 + 1] + v0.z * w[4 * k4 + 2] + v0.w * w[4 * k4 + 3];
                float4 v1 = hb4[k4 + 1];
                a1 += v1.x * w[4 * k4 + 4] + v1.y * w[4 * k4 + 5] + v1.z * w[4 * k4 + 6] + v1.w * w[4 * k4 + 7];
                float4 v2 = hb4[k4 + 2];
                a2 += v2.x * w[4 * k4 + 8] + v2.y * w[4 * k4 + 9] + v2.z * w[4 * k4 + 10] + v2.w * w[4 * k4 + 11];
                float4 v3 = hb4[k4 + 3];
                a3 += v3.x * w[4 * k4 + 12] + v3.y * w[4 * k4 + 13] + v3.z * w[4 * k4 + 14] + v3.w * w[4 * k4 + 15];
            }
            // embedding contribution (emb/ids/Wx are read-only: scalar path safe)
            const int idb = ids[(brow0 + b) * NT + t];
            const float4* eb = reinterpret_cast<const float4*>(emb + (size_t)idb * NE + wv * 8);
            float4 e0 = eb[0], e1 = eb[1];
            a0 += e0.x * wx[0] + e0.y * wx[1] + e0.z * wx[2] + e0.w * wx[3];
            a1 += e1.x * wx[4] + e1.y * wx[5] + e1.z * wx[6] + e1.w * wx[7];
            acc[b] = (a0 + a1) + (a2 + a3);
        }
#pragma unroll
        for (int b = 0; b < 8; ++b) psum[wv][b][cl] = acc[b];
        __syncthreads();

        if (tid < 128) {
            float z[4];
#pragma unroll
            for (int g = 0; g < 4; ++g) {
                float s = b4[g];
#pragma unroll
                for (int w8 = 0; w8 < 8; ++w8) s += psum[w8][bl][g * 16 + uug];
                z[g] = s;
            }
            const float i_ = 1.f / (1.f + expf(-z[0]));
            const float f_ = 1.f / (1.f + expf(-z[1]));
            const float g_ = tanhf(z[2]);
            const float o_ = 1.f / (1.f + expf(-z[3]));
            creg = f_ * creg + i_ * g_;
            const float h_ = o_ * tanhf(creg);
            float* hw = hping + ((t + 1) & 1) * BU;
            const int row = brow0 + bl;
            hw[row * NU + u0 + uug] = h_;
            Hout[((size_t)row * NT + t) * NU + u0 + uug] = h_;
        }
        gg.sync();   // h(t) visible to every block before step t+1
    }
    if (tid < 128) cfin[(brow0 + bl) * NU + u0 + uug] = creg;
}

// ---------------------------------------------------------------------------
// Attention: one wave per (b,q). scores = S_[b,q,:] . H[b,k,:], softmax over
// k, A = sum_k p_k H[b,k,:]. All in registers + 64-lane butterflies.
// Blocks of 4 waves share one b (q0..q0+3) for L1 reuse of H[b].
// ---------------------------------------------------------------------------
__global__ __launch_bounds__(256)
void attn_kernel(const float* __restrict__ S, const float* __restrict__ Hbuf,
                 const float* __restrict__ s0, float* __restrict__ A)
{
    const int tid  = threadIdx.x;
    const int wv   = tid >> 6;
    const int lane = tid & 63;
    const int b    = blockIdx.x >> 5;                 // 0..63
    const int q    = (blockIdx.x & 31) * 4 + wv;      // 0..127

    const float* qrow = (q == 0) ? (s0 + (size_t)b * NU)
                                 : (S + ((size_t)b * NT + (q - 1)) * NU);
    const float4* q4 = reinterpret_cast<const float4*>(qrow);
    const float4 qa = q4[lane], qb = q4[64 + lane];   // u = lane*4+j, 256+lane*4+j
    const float4* Hb = reinterpret_cast<const float4*>(Hbuf + (size_t)b * NT * NU);

    float sr0 = 0.f, sr1 = 0.f;                       // scores for k=lane, 64+lane
    for (int k = 0; k < NT; ++k) {
        const float4* hk = Hb + (size_t)k * 128;
        float4 ha = hk[lane], hc = hk[64 + lane];
        float d = qa.x * ha.x + qa.y * ha.y + qa.z * ha.z + qa.w * ha.w
                + qb.x * hc.x + qb.y * hc.y + qb.z * hc.z + qb.w * hc.w;
#pragma unroll
        for (int o = 32; o; o >>= 1) d += __shfl_xor(d, o);
        if ((k & 63) == lane) { if (k < 64) sr0 = d; else sr1 = d; }
        if ((k & 31) == 31) __syncthreads();          // keep waves aligned for L1 reuse
    }

    float m = fmaxf(sr0, sr1);
#pragma unroll
    for (int o = 32; o; o >>= 1) m = fmaxf(m, __shfl_xor(m, o));
    float e0 = expf(sr0 - m), e1 = expf(sr1 - m);
    float s = e0 + e1;
#pragma unroll
    for (int o = 32; o; o >>= 1) s += __shfl_xor(s, o);
    const float inv = 1.f / s;
    e0 *= inv; e1 *= inv;

    float4 acc0 = {0.f, 0.f, 0.f, 0.f}, acc1 = {0.f, 0.f, 0.f, 0.f};
    for (int k = 0; k < 64; ++k) {
        const float wk = __shfl(e0, k);
        const float4* hk = Hb + (size_t)k * 128;
        float4 ha = hk[lane], hc = hk[64 + lane];
        acc0.x += wk * ha.x; acc0.y += wk * ha.y; acc0.z += wk * ha.z; acc0.w += wk * ha.w;
        acc1.x += wk * hc.x; acc1.y += wk * hc.y; acc1.z += wk * hc.z; acc1.w += wk * hc.w;
        if ((k & 31) == 31) __syncthreads();
    }
    for (int k = 0; k < 64; ++k) {
        const float wk = __shfl(e1, k);
        const float4* hk = Hb + (size_t)(64 + k) * 128;
        float4 ha = hk[lane], hc = hk[64 + lane];
        acc0.x += wk * ha.x; acc0.y += wk * ha.y; acc0.z += wk * ha.z; acc0.w += wk * ha.w;
        acc1.x += wk * hc.x; acc1.y += wk * hc.y; acc1.z += wk * hc.z; acc1.w += wk * hc.w;
        if ((k & 31) == 31) __syncthreads();
    }
    float4* Aq = reinterpret_cast<float4*>(A + ((size_t)b * NT + q) * NU);
    Aq[lane] = acc0;
    Aq[64 + lane] = acc1;
}

// ---------------------------------------------------------------------------
// Dense: logits[r, c] = [S|A][r, :1024] . W[:, c] + bias[c], written to d_out.
// 64x128 tile per block, K staged in LDS chunks of 32.
// ---------------------------------------------------------------------------
__global__ __launch_bounds__(256)
void dense_kernel(const float* __restrict__ S, const float* __restrict__ A,
                  const float* __restrict__ W, const float* __restrict__ bias,
                  float* __restrict__ out)
{
    __shared__ float ys[64][36];       // pad 36: 16B-aligned rows, broadcast reads
    __shared__ float Ws[32][128];
    const int tid = threadIdx.x;
    const int tc = tid & 31, tr = tid >> 5;
    const int c0 = blockIdx.x * 128;
    const int r0 = blockIdx.y * 64;

    float acc[8][4] = {};
    for (int kc = 0; kc < 32; ++kc) {
        const int k0 = kc * 32;
        const float* src = (k0 < 512) ? (S + (size_t)r0 * NU + k0)
                                      : (A + (size_t)r0 * NU + (k0 - 512));
        __syncthreads();
#pragma unroll
        for (int i = 0; i < 8; ++i) {                 // 64x32 yo tile
            int idx = tid + i * 256;
            int row = idx >> 5, kk = idx & 31;
            ys[row][kk] = src[(size_t)row * NU + kk];
        }
#pragma unroll
        for (int i = 0; i < 16; ++i) {                // 32x128 W tile
            int idx = tid + i * 256;
            int kk = idx >> 7, c = idx & 127;
            int cgl = c0 + c;
            Ws[kk][c] = (cgl < NV) ? W[(size_t)(k0 + kk) * NV + cgl] : 0.f;
        }
        __syncthreads();
#pragma unroll
        for (int kk = 0; kk < 32; ++kk) {
            float wv_[4];
#pragma unroll
            for (int cc = 0; cc < 4; ++cc) wv_[cc] = Ws[kk][tc + 32 * cc];
#pragma unroll
            for (int rr = 0; rr < 8; ++rr) {
                float a = ys[tr + 8 * rr][kk];
#pragma unroll
                for (int cc = 0; cc < 4; ++cc) acc[rr][cc] += a * wv_[cc];
            }
        }
    }
#pragma unroll
    for (int rr = 0; rr < 8; ++rr) {
        const int r = r0 + tr + 8 * rr;
#pragma unroll
        for (int cc = 0; cc < 4; ++cc) {
            const int c = c0 + tc + 32 * cc;
            if (c < NV) out[(size_t)r * NV + c] = acc[rr][cc] + bias[c];
        }
    }
}

// ---------------------------------------------------------------------------
// In-place row softmax over V=2000 logits (one block per row).
// ---------------------------------------------------------------------------
__global__ __launch_bounds__(256)
void softmax_rows(float* __restrict__ out)
{
    __shared__ float red[4];
    const int t = threadIdx.x;
    float* row = out + (size_t)blockIdx.x * NV;

    float v[8];
    float m = -INFINITY;
#pragma unroll
    for (int i = 0; i < 8; ++i) {
        const int j = t + 256 * i;
        v[i] = (j < NV) ? row[j] : -INFINITY;
        m = fmaxf(m, v[i]);
    }
#pragma unroll
    for (int o = 32; o; o >>= 1) m = fmaxf(m, __shfl_xor(m, o));
    if ((t & 63) == 0) red[t >> 6] = m;
    __syncthreads();
    m = fmaxf(fmaxf(red[0], red[1]), fmaxf(red[2], red[3]));
    __syncthreads();

    float s = 0.f;
#pragma unroll
    for (int i = 0; i < 8; ++i) {
        const int j = t + 256 * i;
        if (j < NV) { v[i] = expf(v[i] - m); s += v[i]; }
    }
#pragma unroll
    for (int o = 32; o; o >>= 1) s += __shfl_xor(s, o);
    if ((t & 63) == 0) red[t >> 6] = s;
    __syncthreads();
    const float inv = 1.f / (red[0] + red[1] + red[2] + red[3]);
#pragma unroll
    for (int i = 0; i < 8; ++i) {
        const int j = t + 256 * i;
        if (j < NV) row[j] = v[i] * inv;
    }
}

// ---------------------------------------------------------------------------
extern "C" void kernel_launch(void* const* d_in, const int* in_sizes, int n_in,
                              void* d_out, int out_size, void* d_ws, size_t ws_size,
                              hipStream_t stream)
{
    const int*   x       = (const int*)  d_in[0];
    const int*   y       = (const int*)  d_in[1];
    const float* enc_emb = (const float*)d_in[2];
    const float* enc_Wx  = (const float*)d_in[3];
    const float* enc_Wh  = (const float*)d_in[4];
    const float* enc_b   = (const float*)d_in[5];
    const float* dec_emb = (const float*)d_in[6];
    const float* dec_Wx  = (const float*)d_in[7];
    const float* dec_Wh  = (const float*)d_in[8];
    const float* dec_b   = (const float*)d_in[9];
    const float* dns_W   = (const float*)d_in[10];
    const float* dns_b   = (const float*)d_in[11];
    float* out = (float*)d_out;

    float* ws   = (float*)d_ws;
    float* Hbuf = ws;                       // [B,T,U]
    float* Sbuf = Hbuf + (size_t)NB * NT * NU;
    float* Abuf = Sbuf + (size_t)NB * NT * NU;
    float* ehp  = Abuf + (size_t)NB * NT * NU;   // enc h ping-pong [2][B,U]
    float* dhp  = ehp + 2 * BU;                  // dec h ping-pong
    float* cfe  = dhp + 2 * BU;                  // enc final c
    float* cfd  = cfe + BU;                      // dec final c (unused later)

    const float* nul = nullptr;

    {   // encoder LSTM
        void* args[] = { (void*)&enc_emb, (void*)&x, (void*)&enc_Wx, (void*)&enc_Wh,
                         (void*)&enc_b, (void*)&nul, (void*)&nul,
                         (void*)&Hbuf, (void*)&ehp, (void*)&cfe };
        hipLaunchCooperativeKernel(reinterpret_cast<void*>(lstm_coop),
                                   dim3(256), dim3(512), args, 0, stream);
    }
    {   // decoder LSTM: h0 = enc final h (ehp slot0), c0 = enc final c
        const float* h0 = ehp;
        const float* c0 = cfe;
        void* args[] = { (void*)&dec_emb, (void*)&y, (void*)&dec_Wx, (void*)&dec_Wh,
                         (void*)&dec_b, (void*)&h0, (void*)&c0,
                         (void*)&Sbuf, (void*)&dhp, (void*)&cfd };
        hipLaunchCooperativeKernel(reinterpret_cast<void*>(lstm_coop),
                                   dim3(256), dim3(512), args, 0, stream);
    }
    // attention: s0 = enc final h (ehp slot0)
    attn_kernel<<<dim3(NB * 32), dim3(256), 0, stream>>>(Sbuf, Hbuf, ehp, Abuf);
    // dense logits -> d_out
    dense_kernel<<<dim3(16, 128), dim3(256), 0, stream>>>(Sbuf, Abuf, dns_W, dns_b, out);
    // in-place softmax
    softmax_rows<<<dim3(NB * NT), dim3(256), 0, stream>>>(out);
}

// Round 2
// 3329.856 us; speedup vs baseline: 3.5938x; 3.5938x over previous
//
#include <hip/hip_runtime.h>
#include <hip/hip_cooperative_groups.h>
#include <math.h>

#define NB 64       // batch
#define NT 128      // time steps
#define NE 64       // embedding
#define NU 512      // units
#define NG 2048     // 4*U
#define NV 2000     // vocab
#define BU (NB*NU)
#define GRID_LSTM 256

// ---------------------------------------------------------------------------
// Cooperative LSTM: 256 blocks x 512 threads, 1 block/CU (co-resident via
// cooperative launch). Block (rg,cgi): rg=bk>>5 owns rows brow0..+8,
// cgi=bk&31 owns units u0..u0+16 (64 z-cols: 4 gates x 16 units; lane=col).
// Wave wv owns k-slice [wv*64, wv*64+64). Wh stays in VGPRs.
//
// Cross-block h exchange per step uses agent-scope coherent atomics (which
// bypass the per-XCD L2s and hit the coherent memory-side Infinity Cache),
// so the grid barrier needs NO cache writeback/invalidate: per-thread
// s_waitcnt vmcnt(0) + one relaxed atomicAdd arrive per block + relaxed spin.
// This replaces cg::grid.sync() (~41 us/step of wbl2/inv cost).
// h(t) is staged into LDS once per block; the GEMV reads it via uniform
// (broadcast) ds_read_b128.
// ---------------------------------------------------------------------------
__global__ __launch_bounds__(512, 1)
void lstm_coop(const float* __restrict__ emb, const int* __restrict__ ids,
               const float* __restrict__ Wx, const float* __restrict__ Wh,
               const float* __restrict__ bias,
               const float* __restrict__ h0, const float* __restrict__ c0,
               float* __restrict__ Hout, float* __restrict__ hping,
               float* __restrict__ cfin, unsigned int* __restrict__ barcnt)
{
    __shared__ float psum[8][8][64];           // 16 KB
    __shared__ float hlds[8][512];             // 16 KB: h rows brow0..brow0+7

    const int tid  = threadIdx.x;
    const int wv   = tid >> 6;                 // 0..7 k-slice
    const int cl   = tid & 63;                 // column lane
    const int bk   = blockIdx.x;
    const int rg   = bk >> 5;                  // 0..7
    const int cgi  = bk & 31;                  // 0..31
    const int brow0 = rg * 8;
    const int u0    = cgi * 16;
    const int gate  = cl >> 4;                 // 0..3
    const int uu_c  = cl & 15;
    const int colg  = gate * 512 + u0 + uu_c;  // global z column of this lane

    // per-thread weight registers (read-only inputs: plain loads fine)
    float w[64];
#pragma unroll
    for (int kk = 0; kk < 64; ++kk) w[kk] = Wh[(size_t)(wv * 64 + kk) * NG + colg];
    float wx[8];
#pragma unroll
    for (int ee = 0; ee < 8; ++ee) wx[ee] = Wx[(size_t)(wv * 8 + ee) * NG + colg];

    // gate/update threads: tid<128 -> (row bl, unit uug)
    const int bl  = tid >> 4;
    const int uug = tid & 15;
    float creg = 0.f;
    float b4[4] = {0.f, 0.f, 0.f, 0.f};
    if (tid < 128) {
#pragma unroll
        for (int g = 0; g < 4; ++g) b4[g] = bias[g * 512 + u0 + uug];
        if (c0) creg = c0[(brow0 + bl) * NU + u0 + uug];
    }

    // stage h(0) directly into LDS (h0 was written by a prior kernel on this
    // stream -> coherent at kernel start; no barrier needed)
    if (h0) {
        const float* src = h0 + (size_t)brow0 * NU;
#pragma unroll
        for (int j = 0; j < 8; ++j)
            ((float*)hlds)[tid + 512 * j] = src[tid + 512 * j];
    } else {
#pragma unroll
        for (int j = 0; j < 8; ++j)
            ((float*)hlds)[tid + 512 * j] = 0.f;
    }
    __syncthreads();

    int barno = 0;

    for (int t = 0; t < NT; ++t) {
        // ---- z = h @ Wh (k-slice) + x-emb @ Wx, h from LDS (broadcast reads)
        float acc[8];
#pragma unroll
        for (int b = 0; b < 8; ++b) {
            const float4* hb4 = reinterpret_cast<const float4*>(&hlds[b][wv * 64]);
            float a0 = 0.f, a1 = 0.f, a2 = 0.f, a3 = 0.f;
#pragma unroll
            for (int k4 = 0; k4 < 16; k4 += 4) {
                float4 v0 = hb4[k4 + 0];
                a0 += v0.x * w[4 * k4 + 0] + v0.y * w[4 * k4 + 1] + v0.z * w[4 * k4 + 2] + v0.w * w[4 * k4 + 3];
                float4 v1 = hb4[k4 + 1];
                a1 += v1.x * w[4 * k4 + 4] + v1.y * w[4 * k4 + 5] + v1.z * w[4 * k4 + 6] + v1.w * w[4 * k4 + 7];
                float4 v2 = hb4[k4 + 2];
                a2 += v2.x * w[4 * k4 + 8] + v2.y * w[4 * k4 + 9] + v2.z * w[4 * k4 + 10] + v2.w * w[4 * k4 + 11];
                float4 v3 = hb4[k4 + 3];
                a3 += v3.x * w[4 * k4 + 12] + v3.y * w[4 * k4 + 13] + v3.z * w[4 * k4 + 14] + v3.w * w[4 * k4 + 15];
            }
            const int idb = ids[(brow0 + b) * NT + t];
            const float4* eb = reinterpret_cast<const float4*>(emb + (size_t)idb * NE + wv * 8);
            float4 e0 = eb[0], e1 = eb[1];
            a0 += e0.x * wx[0] + e0.y * wx[1] + e0.z * wx[2] + e0.w * wx[3];
            a1 += e1.x * wx[4] + e1.y * wx[5] + e1.z * wx[6] + e1.w * wx[7];
            acc[b] = (a0 + a1) + (a2 + a3);
        }
#pragma unroll
        for (int b = 0; b < 8; ++b) psum[wv][b][cl] = acc[b];
        __syncthreads();

        // ---- gates + state update + coherent h publish
        if (tid < 128) {
            float z[4];
#pragma unroll
            for (int g = 0; g < 4; ++g) {
                float s = b4[g];
#pragma unroll
                for (int w8 = 0; w8 < 8; ++w8) s += psum[w8][bl][g * 16 + uug];
                z[g] = s;
            }
            const float i_ = 1.f / (1.f + expf(-z[0]));
            const float f_ = 1.f / (1.f + expf(-z[1]));
            const float g_ = tanhf(z[2]);
            const float o_ = 1.f / (1.f + expf(-z[3]));
            creg = f_ * creg + i_ * g_;
            const float h_ = o_ * tanhf(creg);
            const int row = brow0 + bl;
            float* hw = hping + ((t + 1) & 1) * BU;
            __hip_atomic_store(&hw[row * NU + u0 + uug], h_,
                               __ATOMIC_RELAXED, __HIP_MEMORY_SCOPE_AGENT);
            Hout[((size_t)row * NT + t) * NU + u0 + uug] = h_;   // plain: read by later kernels
        }
        if (t == NT - 1) break;   // final h/c flushed by kernel-end release

        // ---- lightweight grid barrier (no cache maintenance needed: the h
        // stores above are agent-coherent; vmcnt(0) = completed at coherence pt)
        asm volatile("s_waitcnt vmcnt(0)" ::: "memory");
        __syncthreads();                        // all threads drained
        ++barno;
        if (tid == 0) {
            __hip_atomic_fetch_add(barcnt, 1u, __ATOMIC_RELAXED, __HIP_MEMORY_SCOPE_AGENT);
            const unsigned target = (unsigned)barno * GRID_LSTM;
            while (__hip_atomic_load(barcnt, __ATOMIC_RELAXED, __HIP_MEMORY_SCOPE_AGENT) < target)
                __builtin_amdgcn_s_sleep(1);
        }
        __syncthreads();
        asm volatile("" ::: "memory");          // no compiler hoist of h loads above spin

        // ---- stage h(t+1) into LDS via coherent coalesced loads
        const float* hr = hping + ((t + 1) & 1) * BU + (size_t)brow0 * NU;
        float tmp[8];
#pragma unroll
        for (int j = 0; j < 8; ++j)
            tmp[j] = __hip_atomic_load(const_cast<float*>(&hr[tid + 512 * j]),
                                       __ATOMIC_RELAXED, __HIP_MEMORY_SCOPE_AGENT);
#pragma unroll
        for (int j = 0; j < 8; ++j)
            ((float*)hlds)[tid + 512 * j] = tmp[j];
        __syncthreads();
    }
    if (tid < 128) cfin[(brow0 + bl) * NU + u0 + uug] = creg;
}

// ---------------------------------------------------------------------------
// Attention: one wave per (b,q). scores = S_[b,q,:] . H[b,k,:], softmax over
// k, A = sum_k p_k H[b,k,:]. All in registers + 64-lane butterflies.
// ---------------------------------------------------------------------------
__global__ __launch_bounds__(256)
void attn_kernel(const float* __restrict__ S, const float* __restrict__ Hbuf,
                 const float* __restrict__ s0, float* __restrict__ A)
{
    const int tid  = threadIdx.x;
    const int wv   = tid >> 6;
    const int lane = tid & 63;
    const int b    = blockIdx.x >> 5;                 // 0..63
    const int q    = (blockIdx.x & 31) * 4 + wv;      // 0..127

    const float* qrow = (q == 0) ? (s0 + (size_t)b * NU)
                                 : (S + ((size_t)b * NT + (q - 1)) * NU);
    const float4* q4 = reinterpret_cast<const float4*>(qrow);
    const float4 qa = q4[lane], qb = q4[64 + lane];
    const float4* Hb = reinterpret_cast<const float4*>(Hbuf + (size_t)b * NT * NU);

    float sr0 = 0.f, sr1 = 0.f;
    for (int k = 0; k < NT; ++k) {
        const float4* hk = Hb + (size_t)k * 128;
        float4 ha = hk[lane], hc = hk[64 + lane];
        float d = qa.x * ha.x + qa.y * ha.y + qa.z * ha.z + qa.w * ha.w
                + qb.x * hc.x + qb.y * hc.y + qb.z * hc.z + qb.w * hc.w;
#pragma unroll
        for (int o = 32; o; o >>= 1) d += __shfl_xor(d, o);
        if ((k & 63) == lane) { if (k < 64) sr0 = d; else sr1 = d; }
        if ((k & 31) == 31) __syncthreads();
    }

    float m = fmaxf(sr0, sr1);
#pragma unroll
    for (int o = 32; o; o >>= 1) m = fmaxf(m, __shfl_xor(m, o));
    float e0 = expf(sr0 - m), e1 = expf(sr1 - m);
    float s = e0 + e1;
#pragma unroll
    for (int o = 32; o; o >>= 1) s += __shfl_xor(s, o);
    const float inv = 1.f / s;
    e0 *= inv; e1 *= inv;

    float4 acc0 = {0.f, 0.f, 0.f, 0.f}, acc1 = {0.f, 0.f, 0.f, 0.f};
    for (int k = 0; k < 64; ++k) {
        const float wk = __shfl(e0, k);
        const float4* hk = Hb + (size_t)k * 128;
        float4 ha = hk[lane], hc = hk[64 + lane];
        acc0.x += wk * ha.x; acc0.y += wk * ha.y; acc0.z += wk * ha.z; acc0.w += wk * ha.w;
        acc1.x += wk * hc.x; acc1.y += wk * hc.y; acc1.z += wk * hc.z; acc1.w += wk * hc.w;
        if ((k & 31) == 31) __syncthreads();
    }
    for (int k = 0; k < 64; ++k) {
        const float wk = __shfl(e1, k);
        const float4* hk = Hb + (size_t)(64 + k) * 128;
        float4 ha = hk[lane], hc = hk[64 + lane];
        acc0.x += wk * ha.x; acc0.y += wk * ha.y; acc0.z += wk * ha.z; acc0.w += wk * ha.w;
        acc1.x += wk * hc.x; acc1.y += wk * hc.y; acc1.z += wk * hc.z; acc1.w += wk * hc.w;
        if ((k & 31) == 31) __syncthreads();
    }
    float4* Aq = reinterpret_cast<float4*>(A + ((size_t)b * NT + q) * NU);
    Aq[lane] = acc0;
    Aq[64 + lane] = acc1;
}

// ---------------------------------------------------------------------------
// Dense: logits[r, c] = [S|A][r, :1024] . W[:, c] + bias[c] -> d_out.
// ---------------------------------------------------------------------------
__global__ __launch_bounds__(256)
void dense_kernel(const float* __restrict__ S, const float* __restrict__ A,
                  const float* __restrict__ W, const float* __restrict__ bias,
                  float* __restrict__ out)
{
    __shared__ float ys[64][36];
    __shared__ float Ws[32][128];
    const int tid = threadIdx.x;
    const int tc = tid & 31, tr = tid >> 5;
    const int c0 = blockIdx.x * 128;
    const int r0 = blockIdx.y * 64;

    float acc[8][4] = {};
    for (int kc = 0; kc < 32; ++kc) {
        const int k0 = kc * 32;
        const float* src = (k0 < 512) ? (S + (size_t)r0 * NU + k0)
                                      : (A + (size_t)r0 * NU + (k0 - 512));
        __syncthreads();
#pragma unroll
        for (int i = 0; i < 8; ++i) {
            int idx = tid + i * 256;
            int row = idx >> 5, kk = idx & 31;
            ys[row][kk] = src[(size_t)row * NU + kk];
        }
#pragma unroll
        for (int i = 0; i < 16; ++i) {
            int idx = tid + i * 256;
            int kk = idx >> 7, c = idx & 127;
            int cgl = c0 + c;
            Ws[kk][c] = (cgl < NV) ? W[(size_t)(k0 + kk) * NV + cgl] : 0.f;
        }
        __syncthreads();
#pragma unroll
        for (int kk = 0; kk < 32; ++kk) {
            float wv_[4];
#pragma unroll
            for (int cc = 0; cc < 4; ++cc) wv_[cc] = Ws[kk][tc + 32 * cc];
#pragma unroll
            for (int rr = 0; rr < 8; ++rr) {
                float a = ys[tr + 8 * rr][kk];
#pragma unroll
                for (int cc = 0; cc < 4; ++cc) acc[rr][cc] += a * wv_[cc];
            }
        }
    }
#pragma unroll
    for (int rr = 0; rr < 8; ++rr) {
        const int r = r0 + tr + 8 * rr;
#pragma unroll
        for (int cc = 0; cc < 4; ++cc) {
            const int c = c0 + tc + 32 * cc;
            if (c < NV) out[(size_t)r * NV + c] = acc[rr][cc] + bias[c];
        }
    }
}

// ---------------------------------------------------------------------------
// In-place row softmax over V=2000 logits (one block per row).
// ---------------------------------------------------------------------------
__global__ __launch_bounds__(256)
void softmax_rows(float* __restrict__ out)
{
    __shared__ float red[4];
    const int t = threadIdx.x;
    float* row = out + (size_t)blockIdx.x * NV;

    float v[8];
    float m = -INFINITY;
#pragma unroll
    for (int i = 0; i < 8; ++i) {
        const int j = t + 256 * i;
        v[i] = (j < NV) ? row[j] : -INFINITY;
        m = fmaxf(m, v[i]);
    }
#pragma unroll
    for (int o = 32; o; o >>= 1) m = fmaxf(m, __shfl_xor(m, o));
    if ((t & 63) == 0) red[t >> 6] = m;
    __syncthreads();
    m = fmaxf(fmaxf(red[0], red[1]), fmaxf(red[2], red[3]));
    __syncthreads();

    float s = 0.f;
#pragma unroll
    for (int i = 0; i < 8; ++i) {
        const int j = t + 256 * i;
        if (j < NV) { v[i] = expf(v[i] - m); s += v[i]; }
    }
#pragma unroll
    for (int o = 32; o; o >>= 1) s += __shfl_xor(s, o);
    if ((t & 63) == 0) red[t >> 6] = s;
    __syncthreads();
    const float inv = 1.f / (red[0] + red[1] + red[2] + red[3]);
#pragma unroll
    for (int i = 0; i < 8; ++i) {
        const int j = t + 256 * i;
        if (j < NV) row[j] = v[i] * inv;
    }
}

// ---------------------------------------------------------------------------
extern "C" void kernel_launch(void* const* d_in, const int* in_sizes, int n_in,
                              void* d_out, int out_size, void* d_ws, size_t ws_size,
                              hipStream_t stream)
{
    const int*   x       = (const int*)  d_in[0];
    const int*   y       = (const int*)  d_in[1];
    const float* enc_emb = (const float*)d_in[2];
    const float* enc_Wx  = (const float*)d_in[3];
    const float* enc_Wh  = (const float*)d_in[4];
    const float* enc_b   = (const float*)d_in[5];
    const float* dec_emb = (const float*)d_in[6];
    const float* dec_Wx  = (const float*)d_in[7];
    const float* dec_Wh  = (const float*)d_in[8];
    const float* dec_b   = (const float*)d_in[9];
    const float* dns_W   = (const float*)d_in[10];
    const float* dns_b   = (const float*)d_in[11];
    float* out = (float*)d_out;

    float* ws   = (float*)d_ws;
    float* Hbuf = ws;                                // [B,T,U]
    float* Sbuf = Hbuf + (size_t)NB * NT * NU;
    float* Abuf = Sbuf + (size_t)NB * NT * NU;
    float* ehp  = Abuf + (size_t)NB * NT * NU;       // enc h ping-pong [2][B,U]
    float* dhp  = ehp + 2 * BU;                      // dec h ping-pong
    float* cfe  = dhp + 2 * BU;                      // enc final c
    float* cfd  = cfe + BU;                          // dec final c
    unsigned int* bar0 = (unsigned int*)(cfd + BU);  // barrier counters
    unsigned int* bar1 = bar0 + 64;                  // 256B apart

    hipMemsetAsync(bar0, 0, 512, stream);            // zero both counters

    const float* nul = nullptr;

    {   // encoder LSTM
        void* args[] = { (void*)&enc_emb, (void*)&x, (void*)&enc_Wx, (void*)&enc_Wh,
                         (void*)&enc_b, (void*)&nul, (void*)&nul,
                         (void*)&Hbuf, (void*)&ehp, (void*)&cfe, (void*)&bar0 };
        hipLaunchCooperativeKernel(reinterpret_cast<void*>(lstm_coop),
                                   dim3(GRID_LSTM), dim3(512), args, 0, stream);
    }
    {   // decoder LSTM: h0 = enc final h (ehp slot0), c0 = enc final c
        const float* h0 = ehp;
        const float* c0 = cfe;
        void* args[] = { (void*)&dec_emb, (void*)&y, (void*)&dec_Wx, (void*)&dec_Wh,
                         (void*)&dec_b, (void*)&h0, (void*)&c0,
                         (void*)&Sbuf, (void*)&dhp, (void*)&cfd, (void*)&bar1 };
        hipLaunchCooperativeKernel(reinterpret_cast<void*>(lstm_coop),
                                   dim3(GRID_LSTM), dim3(512), args, 0, stream);
    }
    attn_kernel<<<dim3(NB * 32), dim3(256), 0, stream>>>(Sbuf, Hbuf, ehp, Abuf);
    dense_kernel<<<dim3(16, 128), dim3(256), 0, stream>>>(Sbuf, Abuf, dns_W, dns_b, out);
    softmax_rows<<<dim3(NB * NT), dim3(256), 0, stream>>>(out);
}